// Round 3
// baseline (422.348 us; speedup 1.0000x reference)
//
#include <hip/hip_runtime.h>
#include <hip/hip_bf16.h>
#include <stdint.h>
#include <stddef.h>

typedef __bf16 bf16;
typedef __bf16 bf16x4 __attribute__((ext_vector_type(4)));
typedef __bf16 bf16x8 __attribute__((ext_vector_type(8)));
typedef float f32x4 __attribute__((ext_vector_type(4)));

#define BROWS 16384
#define NDIM 1024
#define NLAYERS 3

// ---------------------------------------------------------------------------
// async global->LDS, 16B per lane. dst must be wave-uniform base (HW adds lane*16).
__device__ __forceinline__ void gld_lds16(const bf16* g, bf16* l) {
    __builtin_amdgcn_global_load_lds(
        (const __attribute__((address_space(1))) void*)g,
        (__attribute__((address_space(3))) void*)l, 16, 0, 0);
}

// ---------------------------------------------------------------------------
// fp32 -> bf16 flat convert (used for V weights and x0)
__global__ __launch_bounds__(256) void cvt_bf16_kernel(
    const float* __restrict__ src, bf16* __restrict__ dst, int n4)
{
    int i = blockIdx.x * 256 + threadIdx.x;
    if (i < n4) {
        float4 v = ((const float4*)src)[i];
        bf16x4 b;
        b[0] = (bf16)v.x; b[1] = (bf16)v.y; b[2] = (bf16)v.z; b[3] = (bf16)v.w;
        ((bf16x4*)dst)[i] = b;
    }
}

// U (fp32 [L,E,N,R]) -> wu bf16 [L, N, E*R]  (transpose e <-> n)
__global__ __launch_bounds__(256) void wu_transpose_kernel(
    const float* __restrict__ U, bf16* __restrict__ wu)
{
    int d = blockIdx.x * 256 + threadIdx.x;      // 3*1024*512 = 1572864 total
    int r = d & 63;
    int e = (d >> 6) & 7;
    int n = (d >> 9) & 1023;
    int l = d >> 19;
    size_t s = (((size_t)(l * 8 + e)) * 1024 + n) * 64 + r;
    wu[d] = (bf16)U[s];
}

// gw fp32 [8,1024] -> gwp bf16 [kt=16][e=16(pad)][k=64]
__global__ __launch_bounds__(256) void gwp_kernel(
    const float* __restrict__ gw, bf16* __restrict__ gwp)
{
    int d = (blockIdx.x * 256 + threadIdx.x) * 4;   // 16384 elems total
    int k  = d & 63;
    int e  = (d >> 6) & 15;
    int kt = d >> 10;
    bf16x4 b = {};
    if (e < 8) {
        float4 v = *(const float4*)&gw[e * 1024 + kt * 64 + k];
        b[0] = (bf16)v.x; b[1] = (bf16)v.y; b[2] = (bf16)v.z; b[3] = (bf16)v.w;
    }
    *(bf16x4*)&gwp[d] = b;
}

// ---------------------------------------------------------------------------
// Fused GEMM1: v = xb @ wv^T, gates = softmax(xb @ gw^T) (via extra MFMA cols),
//              cp = bf16( gate[:,e] * relu( relu(v) @ C[e]^T ) )
// 128x128 block tile; wave tile 64x64 = 1 expert; 4 N-blocks = 8 experts.
template<int KDIM>
__global__ __launch_bounds__(256) void gemm_vc_kernel(
    const bf16* __restrict__ A, const bf16* __restrict__ Bt,
    const float* __restrict__ Cwl, const bf16* __restrict__ gwp,
    bf16* __restrict__ cp)
{
    // As 8192 | Bs 8192 | Cs 8192 | Gs 1024 bf16 elems, then g_lds 128x8 f32.
    __shared__ __align__(16) bf16 smem[27648];
    bf16* As = smem;
    bf16* Bs = smem + 8192;
    bf16* Cs = smem + 16384;
    bf16* Gs = smem + 24576;
    float* g_lds = (float*)(smem + 25600);   // 4 KB

    const int tid = threadIdx.x;
    const int wv = tid >> 6, ln = tid & 63;
    const long bm = (long)blockIdx.y * 128;
    const long bn = (long)blockIdx.x * 128;
    const int wm = (wv >> 1) << 6, wn = (wv & 1) << 6;
    const int e_loc = wv & 1;
    f32x4 acc[4][4] = {};
    f32x4 accg[4] = {};

    // ---- stage C weights for this block's 2 experts (fp32 -> bf16, XOR-swizzled [r][s])
    {
        const float* Cg = Cwl + (size_t)(blockIdx.x * 2) * 4096;
#pragma unroll
        for (int i = 0; i < 8; ++i) {
            int f = tid * 32 + i * 4;
            float4 cv = *(const float4*)&Cg[f];
            int ee = f >> 12;
            int r  = (f >> 6) & 63;
            int s  = f & 63;
            bf16x4 b;
            b[0] = (bf16)cv.x; b[1] = (bf16)cv.y; b[2] = (bf16)cv.z; b[3] = (bf16)cv.w;
            char* base = (char*)Cs + ee * 8192;
            *(bf16x4*)(base + ((r * 128 + s * 2) ^ ((r & 7) << 4))) = b;
        }
    }

    const int srow = tid >> 3;
    const int scol = (tid & 7) * 8;
    const bf16* Abase = A + (bm + srow) * (long)KDIM + scol;
    const bf16* Bbase = Bt + (bn + srow) * (long)KDIM + scol;
    bf16* Asl = &As[(tid & ~63) * 8];
    bf16* Bsl = &Bs[(tid & ~63) * 8];

    for (int kt = 0; kt < KDIM / 64; ++kt) {
        const int k0 = kt * 64;
        __syncthreads();
#pragma unroll
        for (int t = 0; t < 4; ++t) {
            gld_lds16(Abase + (long)t * 32 * KDIM + k0, Asl + t * 2048);
            gld_lds16(Bbase + (long)t * 32 * KDIM + k0, Bsl + t * 2048);
        }
        if (wv == 3) {   // stage gw tile [16 e][64 k] (2 KB)
            gld_lds16(gwp + kt * 1024 + ln * 8, Gs);
            gld_lds16(gwp + kt * 1024 + 512 + ln * 8, Gs + 512);
        }
        __syncthreads();
#pragma unroll
        for (int kc = 0; kc < 2; ++kc) {
            bf16x8 af[4], bfr[4];
#pragma unroll
            for (int i = 0; i < 4; ++i) {
                af[i]  = *(const bf16x8*)&As[(wm + i * 16 + (ln & 15)) * 64 + kc * 32 + (ln >> 4) * 8];
                bfr[i] = *(const bf16x8*)&Bs[(wn + i * 16 + (ln & 15)) * 64 + kc * 32 + (ln >> 4) * 8];
            }
#pragma unroll
            for (int mi = 0; mi < 4; ++mi)
#pragma unroll
                for (int ni = 0; ni < 4; ++ni)
                    acc[mi][ni] = __builtin_amdgcn_mfma_f32_16x16x32_bf16(
                        af[mi], bfr[ni], acc[mi][ni], 0, 0, 0);
            if ((wv & 1) == 0) {   // waves 0,2: gate logits
                bf16x8 gfr = *(const bf16x8*)&Gs[(ln & 15) * 64 + kc * 32 + (ln >> 4) * 8];
#pragma unroll
                for (int mi = 0; mi < 4; ++mi)
                    accg[mi] = __builtin_amdgcn_mfma_f32_16x16x32_bf16(
                        af[mi], gfr, accg[mi], 0, 0, 0);
            }
        }
    }

    __syncthreads();   // everyone done reading As/Bs

    const int cr = (ln >> 4) * 4, cc = ln & 15;

    // ---- gates softmax (waves 0,2): logit[row, e=cc] in accg[mi][j]
    if ((wv & 1) == 0) {
#pragma unroll
        for (int mi = 0; mi < 4; ++mi)
#pragma unroll
            for (int j = 0; j < 4; ++j) {
                float l = accg[mi][j];
                float m = l;
#pragma unroll
                for (int msk = 1; msk <= 4; msk <<= 1)
                    m = fmaxf(m, __shfl_xor(l, msk));
                // second pass for true max (pairwise): redo with running max
                float m2 = l;
                m2 = fmaxf(m2, __shfl_xor(m2, 1));
                m2 = fmaxf(m2, __shfl_xor(m2, 2));
                m2 = fmaxf(m2, __shfl_xor(m2, 4));
                float ex = __expf(l - m2);
                float s = ex;
                s += __shfl_xor(s, 1);
                s += __shfl_xor(s, 2);
                s += __shfl_xor(s, 4);
                if (cc < 8) {
                    int row = wm + mi * 16 + cr + j;
                    g_lds[row * 8 + cc] = ex / s;
                }
            }
    }

    // ---- relu(v) -> per-wave 64x64 bf16 LDS tile (aliases As/Bs), XOR-swizzled
    char* vsb = (char*)smem + wv * 8192;
#pragma unroll
    for (int mi = 0; mi < 4; ++mi)
#pragma unroll
        for (int ni = 0; ni < 4; ++ni)
#pragma unroll
            for (int j = 0; j < 4; ++j) {
                int row = mi * 16 + cr + j;
                int col = ni * 16 + cc;
                *(bf16*)(vsb + ((row * 128 + col * 2) ^ ((row & 7) << 4))) =
                    (bf16)fmaxf(acc[mi][ni][j], 0.f);
            }
    __syncthreads();   // vs + Cs + g_lds visible

    // ---- c = relu(v) @ C[e]^T   (64x64x64 per wave, 32 MFMAs)
    f32x4 acc2[4][4] = {};
    char* csb = (char*)Cs + e_loc * 8192;
#pragma unroll
    for (int kc = 0; kc < 2; ++kc) {
        bf16x8 af[4], bfr[4];
        const int sb = (kc * 32 + (ln >> 4) * 8) * 2;
#pragma unroll
        for (int i = 0; i < 4; ++i) {
            int ra = i * 16 + (ln & 15);
            af[i]  = *(const bf16x8*)(vsb + ((ra * 128 + sb) ^ ((ra & 7) << 4)));
            bfr[i] = *(const bf16x8*)(csb + ((ra * 128 + sb) ^ ((ra & 7) << 4)));
        }
#pragma unroll
        for (int mi = 0; mi < 4; ++mi)
#pragma unroll
            for (int ni = 0; ni < 4; ++ni)
                acc2[mi][ni] = __builtin_amdgcn_mfma_f32_16x16x32_bf16(
                    af[mi], bfr[ni], acc2[mi][ni], 0, 0, 0);
    }

    // ---- epilogue: cp = bf16( g * relu(c) ), g from LDS
    const int e_g = (int)(blockIdx.x * 2) + e_loc;
#pragma unroll
    for (int mi = 0; mi < 4; ++mi)
#pragma unroll
        for (int j = 0; j < 4; ++j) {
            int wrow = wm + mi * 16 + cr + j;
            long row = bm + wrow;
            float g = g_lds[wrow * 8 + e_g];
#pragma unroll
            for (int ni = 0; ni < 4; ++ni) {
                long col = bn + wn + ni * 16 + cc;
                cp[row * 512 + col] = (bf16)(fmaxf(acc2[mi][ni][j], 0.f) * g);
            }
        }
}

// ---------------------------------------------------------------------------
// GEMM2: u = cp @ wu^T (128x64 tile), epilogue:
//   out = xl + mul*(u + bias),  mul = XL_IS_X0 ? xl : bf16_x0
//   optionally xbn = bf16(out)
template<bool XL_IS_X0, bool WRITE_XB>
__global__ __launch_bounds__(256) void gemm2_kernel(
    const bf16* __restrict__ A, const bf16* __restrict__ Bt,
    const float* __restrict__ xl, const bf16* __restrict__ xb0,
    const float* __restrict__ bias, float* __restrict__ out,
    bf16* __restrict__ xbn)
{
    __shared__ __align__(16) bf16 As[128 * 64];
    __shared__ __align__(16) bf16 Bs[64 * 64];
    const int tid = threadIdx.x;
    const int wv = tid >> 6, ln = tid & 63;
    const long bm = (long)blockIdx.y * 128;
    const long bn = (long)blockIdx.x * 64;
    const int wm = (wv >> 1) << 6, wn = (wv & 1) << 5;
    f32x4 acc[4][2] = {};

    const int srow = tid >> 3;
    const int scol = (tid & 7) * 8;
    const bf16* Abase = A + (bm + srow) * 512L + scol;
    const bf16* Bbase = Bt + (bn + srow) * 512L + scol;
    bf16* Asl = &As[(tid & ~63) * 8];
    bf16* Bsl = &Bs[(tid & ~63) * 8];

    for (int kt = 0; kt < 8; ++kt) {
        const int k0 = kt * 64;
        __syncthreads();
#pragma unroll
        for (int t = 0; t < 4; ++t)
            gld_lds16(Abase + (long)t * 32 * 512 + k0, Asl + t * 2048);
#pragma unroll
        for (int t = 0; t < 2; ++t)
            gld_lds16(Bbase + (long)t * 32 * 512 + k0, Bsl + t * 2048);
        __syncthreads();
#pragma unroll
        for (int kc = 0; kc < 2; ++kc) {
            bf16x8 af[4], bfr[2];
#pragma unroll
            for (int i = 0; i < 4; ++i)
                af[i]  = *(const bf16x8*)&As[(wm + i * 16 + (ln & 15)) * 64 + kc * 32 + (ln >> 4) * 8];
#pragma unroll
            for (int i = 0; i < 2; ++i)
                bfr[i] = *(const bf16x8*)&Bs[(wn + i * 16 + (ln & 15)) * 64 + kc * 32 + (ln >> 4) * 8];
#pragma unroll
            for (int mi = 0; mi < 4; ++mi)
#pragma unroll
                for (int ni = 0; ni < 2; ++ni)
                    acc[mi][ni] = __builtin_amdgcn_mfma_f32_16x16x32_bf16(
                        af[mi], bfr[ni], acc[mi][ni], 0, 0, 0);
        }
    }

    const int cr = (ln >> 4) * 4, cc = ln & 15;
#pragma unroll
    for (int mi = 0; mi < 4; ++mi)
#pragma unroll
        for (int ni = 0; ni < 2; ++ni) {
            long col = bn + wn + ni * 16 + cc;
            float bcol = bias[col];
#pragma unroll
            for (int j = 0; j < 4; ++j) {
                long row = bm + wm + mi * 16 + cr + j;
                long idx = row * 1024L + col;
                float xlv = xl[idx];
                float mul = XL_IS_X0 ? xlv : (float)xb0[idx];
                float o = xlv + mul * (acc[mi][ni][j] + bcol);
                out[idx] = o;
                if (WRITE_XB) xbn[idx] = (bf16)o;
            }
        }
}

// ---------------------------------------------------------------------------
extern "C" void kernel_launch(void* const* d_in, const int* in_sizes, int n_in,
                              void* d_out, int out_size, void* d_ws, size_t ws_size,
                              hipStream_t stream)
{
    const float* x0   = (const float*)d_in[0];
    const float* U    = (const float*)d_in[1];
    const float* V    = (const float*)d_in[2];
    const float* Cw   = (const float*)d_in[3];
    const float* bias = (const float*)d_in[4];
    const float* gw   = (const float*)d_in[5];
    float* out = (float*)d_out;

    char* ws = (char*)d_ws;
    bf16*  wvw  = (bf16*)ws;                              // 3 MB
    bf16*  wu   = (bf16*)(ws + 3145728);                  // 3 MB
    bf16*  gwp  = (bf16*)(ws + 6291456);                  // 32 KB
    bf16*  xb0  = (bf16*)(ws + 6324224);                  // 32 MB
    bf16*  xbn  = (bf16*)(ws + 6324224 + 33554432);       // 32 MB
    bf16*  cp   = (bf16*)(ws + 6324224 + 2 * 33554432);   // 16 MB

    // weight/x prep (same work every call)
    cvt_bf16_kernel<<<1536, 256, 0, stream>>>(V, wvw, 393216);
    cvt_bf16_kernel<<<16384, 256, 0, stream>>>(x0, xb0, 4194304);
    wu_transpose_kernel<<<6144, 256, 0, stream>>>(U, wu);
    gwp_kernel<<<16, 256, 0, stream>>>(gw, gwp);

    for (int l = 0; l < NLAYERS; ++l) {
        const bf16* xbl = (l == 0) ? xb0 : xbn;
        const float* xl = (l == 0) ? x0 : out;
        gemm_vc_kernel<1024><<<dim3(4, 128), 256, 0, stream>>>(
            xbl, wvw + (size_t)l * 524288, Cw + (size_t)l * 32768, gwp, cp);
        const bf16* wul = wu + (size_t)l * 524288;
        const float* bl = bias + (size_t)l * 1024;
        if (l == 0)
            gemm2_kernel<true, true><<<dim3(16, 128), 256, 0, stream>>>(
                cp, wul, xl, nullptr, bl, out, xbn);
        else if (l == 1)
            gemm2_kernel<false, true><<<dim3(16, 128), 256, 0, stream>>>(
                cp, wul, xl, xb0, bl, out, xbn);
        else
            gemm2_kernel<false, false><<<dim3(16, 128), 256, 0, stream>>>(
                cp, wul, xl, xb0, bl, out, nullptr);
    }
}